// Round 3
// baseline (406.418 us; speedup 1.0000x reference)
//
#include <hip/hip_runtime.h>

// y[n] = x[n] + ALPHA * y[n-1], zero init, per row. 64 rows x 960000 fp32.
// Chunked parallel scan: alpha^256 ~ 8.7e-19 => 256-sample warm-up lookback
// makes chunks independent to well below fp32 precision.
//
// R3: LDS-staged, perfectly coalesced global float4 loads/stores.
// (R2 failed to compile: __builtin_nontemporal_store needs a clang vector
// type, not HIP's float4 class — use ext_vector_type(4).)

#define ALPHA 0.85f

typedef float vf4 __attribute__((ext_vector_type(4)));

constexpr int ROW    = 960000;
constexpr int T      = 16;           // elements per thread
constexpr int BT     = 256;          // threads per block
constexpr int TOT    = T * BT;       // 4096-element window
constexpr int LOOK   = 256;          // warm-up lookback (16 threads' worth)
constexpr int CHUNK  = TOT - LOOK;   // 3840 outputs per block
constexpr int CHUNKS = ROW / CHUNK;  // 250 (exact)
constexpr int LSTRIDE = 20;          // LDS words per thread region (pad 16->20)

// alpha^n evaluated at compile time (double accumulate, cast to float).
constexpr float apow(int n) {
    double r = 1.0;
    for (int i = 0; i < n; ++i) r *= 0.85;
    return (float)r;
}

constexpr float A16   = apow(16);
constexpr float A32   = apow(32);
constexpr float A64   = apow(64);
constexpr float A128  = apow(128);
constexpr float A256  = apow(256);
constexpr float A512  = apow(512);
constexpr float A1024 = apow(1024);          // underflows to 0.0f — fine
constexpr float LOG2_A16 = -3.7514440648f;   // 16 * log2(0.85)

__global__ __launch_bounds__(BT) void deemph_kernel(const float* __restrict__ x,
                                                    float* __restrict__ y) {
    __shared__ float lds[BT * LSTRIDE];      // 20 KB

    const int blk = blockIdx.x;
    const int r   = blk / CHUNKS;
    const int c   = blk - r * CHUNKS;
    const int t   = threadIdx.x;

    const long long rowbase = (long long)r * ROW;
    const long long win0    = rowbase + (long long)c * CHUNK - LOOK; // window elem 0

    // ---- phase 1: coalesced global load -> padded LDS.
    // float4 index p4 = t + 256k covers the 1024 float4s of the window.
    #pragma unroll
    for (int k = 0; k < 4; ++k) {
        const int p4 = t + BT * k;
        const int e  = p4 << 2;              // window element index
        vf4 q;
        if (c == 0 && e < LOOK) {            // pre-row state: zeros (t<64 && k==0)
            q = (vf4){0.f, 0.f, 0.f, 0.f};
        } else {
            q = *(const vf4*)(x + win0 + e);
        }
        const int owner = e >> 4, off = e & 15;
        *(vf4*)&lds[owner * LSTRIDE + off] = q;
    }
    __syncthreads();

    // ---- phase 2: per-thread contiguous fragment from LDS (16 B aligned)
    float v[T];
    #pragma unroll
    for (int j = 0; j < T / 4; ++j) {
        vf4 q = *(const vf4*)&lds[t * LSTRIDE + 4 * j];
        v[4*j+0] = q.x; v[4*j+1] = q.y; v[4*j+2] = q.z; v[4*j+3] = q.w;
    }

    // ---- local sequential scan (zero init)
    float s = 0.0f;
    #pragma unroll
    for (int i = 0; i < T; ++i) { s = v[i] + ALPHA * s; v[i] = s; }

    // ---- wave-level weighted Kogge-Stone inclusive scan of segment sums
    const int lane = t & 63;
    float acc = s;
    {
        float up;
        up = __shfl_up(acc, 1, 64);  if (lane >= 1)  acc += A16  * up;
        up = __shfl_up(acc, 2, 64);  if (lane >= 2)  acc += A32  * up;
        up = __shfl_up(acc, 4, 64);  if (lane >= 4)  acc += A64  * up;
        up = __shfl_up(acc, 8, 64);  if (lane >= 8)  acc += A128 * up;
        up = __shfl_up(acc, 16, 64); if (lane >= 16) acc += A256 * up;
        up = __shfl_up(acc, 32, 64); if (lane >= 32) acc += A512 * up;
    }

    // ---- cross-wave combine (4 waves)
    __shared__ float wsum[BT / 64];
    const int wave = t >> 6;
    if (lane == 63) wsum[wave] = acc;
    __syncthreads();
    float W = 0.0f;                          // state at start of this wave
    for (int w2 = 0; w2 < wave; ++w2) W = wsum[w2] + A1024 * W;

    // exclusive per-lane prefix within wave
    float excl = __shfl_up(acc, 1, 64);
    if (lane == 0) excl = 0.0f;
    const float P = excl + exp2f((float)lane * LOG2_A16) * W;

    // ---- phase 3: apply prefix, write back to own LDS region.
    // Region t is read only by thread t (phase 2) and written only by thread t
    // here, so no barrier needed between phase 2 and phase 3.
    {
        float m = ALPHA;
        #pragma unroll
        for (int j = 0; j < T / 4; ++j) {
            vf4 q;
            q.x = v[4*j+0] + m * P; m *= ALPHA;
            q.y = v[4*j+1] + m * P; m *= ALPHA;
            q.z = v[4*j+2] + m * P; m *= ALPHA;
            q.w = v[4*j+3] + m * P; m *= ALPHA;
            *(vf4*)&lds[t * LSTRIDE + 4 * j] = q;
        }
    }
    __syncthreads();

    // ---- phase 4: coalesced non-temporal store of the 3840-float chunk.
    // chunk float4 index p4 = t + 256k, valid while p4 < 960.
    const long long outbase = rowbase + (long long)c * CHUNK;
    #pragma unroll
    for (int k = 0; k < 4; ++k) {
        const int p4 = t + BT * k;
        if (p4 < CHUNK / 4) {
            const int e = LOOK + (p4 << 2);  // window element index
            const int owner = e >> 4, off = e & 15;
            const vf4 q = *(const vf4*)&lds[owner * LSTRIDE + off];
            __builtin_nontemporal_store(q, (vf4*)(y + outbase + (p4 << 2)));
        }
    }
}

extern "C" void kernel_launch(void* const* d_in, const int* in_sizes, int n_in,
                              void* d_out, int out_size, void* d_ws, size_t ws_size,
                              hipStream_t stream) {
    const float* x = (const float*)d_in[0];
    float* y = (float*)d_out;
    const int nrows = in_sizes[0] / ROW;     // 64
    deemph_kernel<<<dim3(nrows * CHUNKS), dim3(BT), 0, stream>>>(x, y);
}